// Round 3
// baseline (1384.167 us; speedup 1.0000x reference)
//
#include <hip/hip_runtime.h>
#include <hip/hip_cooperative_groups.h>

namespace cg = cooperative_groups;

// ============================================================================
// TemporalPointNet (PointNet++ style) forward on MI355X.
// B=2, T=4 -> BT=8 "batches", N=4096 points, 4 coords (xyz + t).
// SA1: npoint=512, r=0.2, K=32, C_in=4,  MLP 64,64,128
// SA2: npoint=128, r=0.4, K=64, C_in=131, MLP 128,128,256
// SA3: group_all,          K=128, C_in=259, MLP 256,512,1024
// Output: (2,4,1024) f32 = 8192 floats.
//
// R14: cooperative SA1 fusion.
//  (a) sa1_fused: ONE hipLaunchCooperativeKernel replaces the entire SA1 MLP
//      chain (3 gemm + 3 finalize_bn + bn_relu_max). 512 blocks x 256 thr,
//      2 blocks/CU (launch_bounds(256,2), 45KB LDS). Each block owns tiles
//      bx and bx+512 (128 rows each); layer outputs stay IN REGISTERS across
//      grid.sync() — Y0/Y1/Y2 never touch HBM (saves ~266MB traffic + 6
//      dispatch boundaries). B-frags read direct from L2-resident WH/WL.
//      GEMM arithmetic bit-identical to R13 (same split/MFMA order); only
//      BN-stats partial-sum grouping changes (double-prec, ~1e-16).
//      Fallback: if cooperative launch errors, run the R13 dispatch chain.
//  (b) fps_wave piggyback moves from L1_2 (now gone) to qb_group1 extra
//      blocks (input nx1 ready; outputs consumed post-stream-order).
//  (c) fps_block/fps_wave critical chains BYTE-IDENTICAL to R11/R13 measured
//      best (286us). prep_w piggyback in fps_block kept.
// GEMM (SA2/SA3): split-bf16 triple MFMA + fused BN stats (absmax 0.03125).
// ============================================================================

typedef short s16x8 __attribute__((ext_vector_type(8)));
typedef float f32x4 __attribute__((ext_vector_type(4)));

__device__ __forceinline__ unsigned short f2bf_rne(float f) {
    unsigned u = __float_as_uint(f);
    u += 0x7FFFu + ((u >> 16) & 1u);
    return (unsigned short)(u >> 16);
}
// split f32 -> (hi, lo) bf16 pair: hi = rne(v), lo = rne(v - hi)
__device__ __forceinline__ void f2bf_split(float v, unsigned short& hi,
                                           unsigned short& lo) {
    unsigned u = __float_as_uint(v);
    unsigned r = u + 0x7FFFu + ((u >> 16) & 1u);
    hi = (unsigned short)(r >> 16);
    float vh = __uint_as_float(r & 0xFFFF0000u);
    lo = f2bf_rne(v - vh);
}

__device__ __forceinline__ unsigned long long umax64(unsigned long long a,
                                                     unsigned long long b) {
    return a > b ? a : b;
}

// Wave64 max-reduce via DPP: 1 DPP + 1 max per step (R9 measured-best;
// R10 64-bit fused and R12 reg-tracking variants both regressed).
__device__ __forceinline__ unsigned wred_umax63(unsigned v) {
    unsigned t;
    t = (unsigned)__builtin_amdgcn_update_dpp(0, (int)v, 0x111, 0xf, 0xf, true); if (t > v) v = t;
    t = (unsigned)__builtin_amdgcn_update_dpp(0, (int)v, 0x112, 0xf, 0xf, true); if (t > v) v = t;
    t = (unsigned)__builtin_amdgcn_update_dpp(0, (int)v, 0x114, 0xf, 0xf, true); if (t > v) v = t;
    t = (unsigned)__builtin_amdgcn_update_dpp(0, (int)v, 0x118, 0xf, 0xf, true); if (t > v) v = t;
    t = (unsigned)__builtin_amdgcn_update_dpp(0, (int)v, 0x142, 0xa, 0xf, true); if (t > v) v = t;
    t = (unsigned)__builtin_amdgcn_update_dpp(0, (int)v, 0x143, 0xc, 0xf, true); if (t > v) v = t;
    return v;
}

// Wave argmax of (dist, min-index). Exact first-occurrence argmax.
__device__ __forceinline__ void wave_argmax(unsigned dbits, unsigned nInv,
                                            unsigned& vmax, unsigned& iInv) {
    unsigned m = wred_umax63(dbits);
    vmax = (unsigned)__builtin_amdgcn_readlane((int)m, 63);
    unsigned cand = (dbits == vmax) ? nInv : 0u;
    unsigned im = wred_umax63(cand);
    iInv = (unsigned)__builtin_amdgcn_readlane((int)im, 63);
}

// ---------------- all-layer weight pre-split (device body) ----------------
struct PWArgs {
    const float* w[9];
    unsigned off[9];
    int O[9], C[9], CP[9];
};
__device__ __forceinline__ void prep_w_dev(const PWArgs& a,
                                           unsigned short* __restrict__ wh,
                                           unsigned short* __restrict__ wl,
                                           int i) {
    int l = 0;
#pragma unroll
    for (int k = 1; k < 9; ++k) if (i >= (int)a.off[k]) l = k;
    int li = i - (int)a.off[l];
    int CP = a.CP[l];
    int o = li / CP;
    int c = li - o * CP;
    float v = (c < a.C[l]) ? a.w[l][(size_t)o * a.C[l] + c] : 0.f;
    unsigned short h, lo;
    f2bf_split(v, h, lo);
    wh[i] = h; wl[i] = lo;
}

// ---------------- FPS (multi-wave): one block (NT thr) per batch ------------
// R7/R9 structure (measured best 286us). Blocks >= nFps run the weight
// pre-split (fully hidden in the FPS shadow).
template<int NT, int ITEMS, int STRIDE>
__global__ __launch_bounds__(NT) void fps_block(
    const float* __restrict__ pts, int npoint,
    int* __restrict__ outIdx, float* __restrict__ outXyz,
    int nFps, PWArgs pw, unsigned short* __restrict__ wh,
    unsigned short* __restrict__ wl, int wtotal)
{
    constexpr int N = NT * ITEMS;
    constexpr int NW = NT / 64;
    __shared__ float4 scoord[N];
    __shared__ unsigned long long wkey[2][NW];

    if (blockIdx.x >= nFps) {   // piggyback: weight split on idle CUs
        int i = (blockIdx.x - nFps) * NT + threadIdx.x;
        if (i < wtotal) prep_w_dev(pw, wh, wl, i);
        return;
    }

    const int b = blockIdx.x;
    const int tid = threadIdx.x;
    const int wid = tid >> 6;
    const int lane = tid & 63;
    const float* P = pts + (size_t)b * N * STRIDE;

    float px[ITEMS], py[ITEMS], pz[ITEMS], dloc[ITEMS];
#pragma unroll
    for (int w = 0; w < ITEMS; ++w) {
        int n = tid + w * NT;
        float x, y, z;
        if (STRIDE == 4) {
            float4 v = *(const float4*)(P + (size_t)n * 4);
            x = v.x; y = v.y; z = v.z;
        } else {
            x = P[(size_t)n * STRIDE + 0];
            y = P[(size_t)n * STRIDE + 1];
            z = P[(size_t)n * STRIDE + 2];
        }
        px[w] = x; py[w] = y; pz[w] = z;
        scoord[n] = make_float4(x, y, z, 0.f);
        dloc[w] = 1e10f;
    }
    __syncthreads();
    float4 c0 = scoord[0];
    float cx = c0.x, cy = c0.y, cz = c0.z;
    int far = 0;

    for (int i = 0; i < npoint; ++i) {
        if (tid == 0) {
            outIdx[(size_t)b * npoint + i] = far;
            outXyz[((size_t)b * npoint + i) * 3 + 0] = cx;
            outXyz[((size_t)b * npoint + i) * 3 + 1] = cy;
            outXyz[((size_t)b * npoint + i) * 3 + 2] = cz;
        }
        float bestV = -1.0f;
        int bestW = 0;
#pragma unroll
        for (int w = 0; w < ITEMS; ++w) {
            float dx = __fsub_rn(px[w], cx);
            float dy = __fsub_rn(py[w], cy);
            float dz = __fsub_rn(pz[w], cz);
            float d = __fadd_rn(__fadd_rn(__fmul_rn(dx, dx), __fmul_rn(dy, dy)),
                                __fmul_rn(dz, dz));
            float dd = fminf(dloc[w], d);
            dloc[w] = dd;
            if (dd > bestV) { bestV = dd; bestW = w; }  // strict > : lowest w kept
        }
        int bestN = tid + bestW * NT;   // n grows with w -> min n on tie
        unsigned vmax, iInv;
        wave_argmax(__float_as_uint(bestV), 0xFFFFFFFFu ^ (unsigned)bestN,
                    vmax, iInv);
        const int par = i & 1;
        if (lane == 0)
            wkey[par][wid] = ((unsigned long long)vmax << 32) | iInv;
        __syncthreads();   // single barrier per iteration (parity dbuf)
        unsigned long long kb = wkey[par][0];
#pragma unroll
        for (int w2 = 1; w2 < NW; ++w2) kb = umax64(kb, wkey[par][w2]);
        far = (int)(0xFFFFFFFFu ^ (unsigned)kb);
        float4 cc = scoord[far];   // broadcast, conflict-free
        cx = cc.x; cy = cc.y; cz = cc.z;
    }
}

// ---------------- FPS (single wave, device body, no barriers) ---------------
__device__ void fps_wave_dev(const float* __restrict__ pts, int npoint,
                             int* __restrict__ outIdx, float* __restrict__ outXyz,
                             int b, float4* scoord)
{
    constexpr int ITEMS = 8;
    constexpr int STRIDE = 3;
    constexpr int N = 64 * ITEMS;
    const int tid = threadIdx.x;   // 0..63
    const float* P = pts + (size_t)b * N * STRIDE;

    float px[ITEMS], py[ITEMS], pz[ITEMS], dloc[ITEMS];
#pragma unroll
    for (int w = 0; w < ITEMS; ++w) {
        int n = tid + w * 64;
        float x = P[(size_t)n * STRIDE + 0];
        float y = P[(size_t)n * STRIDE + 1];
        float z = P[(size_t)n * STRIDE + 2];
        px[w] = x; py[w] = y; pz[w] = z;
        scoord[n] = make_float4(x, y, z, 0.f);
        dloc[w] = 1e10f;
    }
    __threadfence_block();
    float4 c0 = scoord[0];
    float cx = c0.x, cy = c0.y, cz = c0.z;
    int far = 0;

    for (int i = 0; i < npoint; ++i) {
        if (tid == 0) {
            outIdx[(size_t)b * npoint + i] = far;
            outXyz[((size_t)b * npoint + i) * 3 + 0] = cx;
            outXyz[((size_t)b * npoint + i) * 3 + 1] = cy;
            outXyz[((size_t)b * npoint + i) * 3 + 2] = cz;
        }
        float bestV = -1.0f;
        int bestW = 0;
#pragma unroll
        for (int w = 0; w < ITEMS; ++w) {
            float dx = __fsub_rn(px[w], cx);
            float dy = __fsub_rn(py[w], cy);
            float dz = __fsub_rn(pz[w], cz);
            float d = __fadd_rn(__fadd_rn(__fmul_rn(dx, dx), __fmul_rn(dy, dy)),
                                __fmul_rn(dz, dz));
            float dd = fminf(dloc[w], d);
            dloc[w] = dd;
            if (dd > bestV) { bestV = dd; bestW = w; }
        }
        int bestN = tid + bestW * 64;
        unsigned vmax, iInv;
        wave_argmax(__float_as_uint(bestV), 0xFFFFFFFFu ^ (unsigned)bestN,
                    vmax, iInv);
        far = (int)(0xFFFFFFFFu ^ iInv);
        float4 cc = scoord[far];
        cx = cc.x; cy = cc.y; cz = cc.z;
    }
}

// ---------------- fused query_ball + group for SA1 (+fps_wave piggyback) ----
__global__ __launch_bounds__(256) void qb_group1(
    const float* __restrict__ xyz /*(8,4096,4)*/,
    const float* __restrict__ ctr /*(8*512,3)*/,
    float* __restrict__ out /*(8*512*32, 8)*/,
    int nQb, const float* __restrict__ fpsPts,
    int* __restrict__ fpsIdx, float* __restrict__ fpsXyz)
{
    __shared__ float4 scoord[512];
    if ((int)blockIdx.x >= nQb) {   // piggyback: single-wave FPS (SA2)
        if (threadIdx.x < 64)
            fps_wave_dev(fpsPts, 128, fpsIdx, fpsXyz,
                         (int)blockIdx.x - nQb, scoord);
        return;
    }
    int gw = (blockIdx.x * 256 + threadIdx.x) >> 6;
    int lane = threadIdx.x & 63;
    if (gw >= 4096) return;
    int b = gw >> 9;
    const float* P = xyz + (size_t)b * 4096 * 4;
    float cx = ctr[(size_t)gw * 3 + 0];
    float cy = ctr[(size_t)gw * 3 + 1];
    float cz = ctr[(size_t)gw * 3 + 2];
    float* out0 = out + (size_t)gw * 32 * 8;
    int cnt = 0;
    float f0x = 0.f, f0y = 0.f, f0z = 0.f, f0t = 0.f;
    bool haveFirst = false;
    for (int base = 0; base < 4096 && cnt < 32; base += 64) {
        int n = base + lane;
        float4 p = *(const float4*)(P + (size_t)n * 4);
        float ex = __fsub_rn(p.x, cx);
        float ey = __fsub_rn(p.y, cy);
        float ez = __fsub_rn(p.z, cz);
        float d = __fadd_rn(__fadd_rn(__fmul_rn(ex, ex), __fmul_rn(ey, ey)),
                            __fmul_rn(ez, ez));
        bool inb = !(d > 0.04f);
        unsigned long long mask = __ballot(inb);
        if (mask) {
            if (!haveFirst) {
                int fl = (int)__builtin_ctzll(mask);   // wave-uniform
                f0x = __shfl(ex, fl); f0y = __shfl(ey, fl);
                f0z = __shfl(ez, fl); f0t = __shfl(p.w, fl);
                haveFirst = true;
            }
            if (inb) {
                int pos = cnt + __builtin_popcountll(mask & ((1ull << lane) - 1ull));
                if (pos < 32) {
                    float* o = out0 + (size_t)pos * 8;
                    *(float4*)o = make_float4(ex, ey, ez, p.w);
                    *(float4*)(o + 4) = make_float4(0.f, 0.f, 0.f, 0.f);
                }
            }
            cnt += (int)__builtin_popcountll(mask);
        }
    }
    if (cnt > 32) cnt = 32;
    for (int p2 = cnt + lane; p2 < 32; p2 += 64) {
        float* o = out0 + (size_t)p2 * 8;
        *(float4*)o = make_float4(f0x, f0y, f0z, f0t);
        *(float4*)(o + 4) = make_float4(0.f, 0.f, 0.f, 0.f);
    }
}

// ---------------- query_ball (index-emitting, SA2) ----------------
__global__ __launch_bounds__(256) void query_ball_kernel(
    const float* __restrict__ xyz, int stride, int N,
    const float* __restrict__ centers, int nCenters, int S,
    float r2, int nsample, int* __restrict__ outIdx)
{
    int gw = (blockIdx.x * 256 + threadIdx.x) >> 6;
    int lane = threadIdx.x & 63;
    if (gw >= nCenters) return;
    int b = gw / S;
    const float* P = xyz + (size_t)b * N * stride;
    float cx = centers[(size_t)gw * 3 + 0];
    float cy = centers[(size_t)gw * 3 + 1];
    float cz = centers[(size_t)gw * 3 + 2];
    int* out = outIdx + (size_t)gw * nsample;
    int cnt = 0;
    int firstIdx = 0;
    bool haveFirst = false;
    for (int base = 0; base < N && cnt < nsample; base += 64) {
        int n = base + lane;
        bool inb = false;
        if (n < N) {
            float dx = __fsub_rn(cx, P[(size_t)n * stride + 0]);
            float dy = __fsub_rn(cy, P[(size_t)n * stride + 1]);
            float dz = __fsub_rn(cz, P[(size_t)n * stride + 2]);
            float d = __fadd_rn(__fadd_rn(__fmul_rn(dx, dx), __fmul_rn(dy, dy)),
                                __fmul_rn(dz, dz));
            inb = !(d > r2);
        }
        unsigned long long mask = __ballot(inb);
        if (mask) {
            if (!haveFirst) { firstIdx = base + __builtin_ctzll(mask); haveFirst = true; }
            if (inb) {
                int pos = cnt + __builtin_popcountll(mask & ((1ull << lane) - 1ull));
                if (pos < nsample) out[pos] = n;
            }
            cnt += (int)__builtin_popcountll(mask);
        }
    }
    if (cnt > nsample) cnt = nsample;
    for (int p = cnt + lane; p < nsample; p += 64) out[p] = firstIdx;
}

// ---------------- grouping kernels (f32, padded rows) ----------------------
__global__ __launch_bounds__(256) void group2_kernel(
    const float* __restrict__ xyz, const float* __restrict__ feat,
    const int* __restrict__ qb, const float* __restrict__ ctr,
    float* __restrict__ out)
{
    int i = blockIdx.x * 256 + threadIdx.x;
    if (i >= 65536 * 136) return;
    int sk = i / 136;
    int c = i - sk * 136;
    int b = sk / (128 * 64);
    int bs = sk / 64;
    int idx = qb[sk];
    idx = (idx < 0) ? 0 : (idx > 511 ? 511 : idx);
    float v = 0.f;
    if (c < 3)        v = __fsub_rn(xyz[((size_t)b * 512 + idx) * 3 + c], ctr[(size_t)bs * 3 + c]);
    else if (c < 131) v = feat[((size_t)b * 512 + idx) * 128 + (c - 3)];
    out[i] = v;
}

__global__ __launch_bounds__(256) void group3_kernel(
    const float* __restrict__ ctr2, const float* __restrict__ feat2,
    float* __restrict__ out)
{
    int i = blockIdx.x * 256 + threadIdx.x;
    if (i >= 1024 * 264) return;
    int sk = i / 264;
    int c = i - sk * 264;
    float v = 0.f;
    if (c < 3)        v = ctr2[(size_t)sk * 3 + c];
    else if (c < 259) v = feat2[(size_t)sk * 256 + (c - 3)];
    out[i] = v;
}

// ============================================================================
// SA1 cooperative fused MLP. 512 blocks x 256 thr, 2 blocks/CU.
// Each block: tiles bx, bx+512 (128 rows). Layer Y lives in acc registers
// across grid.sync(); A staged reg->LDS (full K<=64, pitch 72); B-frags
// direct from global (L2-resident weights). Stats/finalize exactly mirror
// gemm_fused/finalize_bn math (fixed deterministic order).
// ============================================================================
#define SA1_PITCH 72

template<int NCHUNK, int CPWv, int Ov>
__device__ __forceinline__ void sa1_gemm(f32x4 (&acc)[4][4],
    const unsigned short* sAh, const unsigned short* sAl,
    const unsigned short* __restrict__ Bh, const unsigned short* __restrict__ Bl,
    int wm, int wo, int col15, int quad)
{
#pragma unroll
    for (int mt = 0; mt < 4; ++mt)
#pragma unroll
        for (int ot = 0; ot < 4; ++ot) acc[mt][ot] = {0.f, 0.f, 0.f, 0.f};
#pragma unroll
    for (int ch = 0; ch < NCHUNK; ++ch) {
        const int k0 = ch * 32;
        s16x8 ah[4], al[4], bh[4], bl[4];
#pragma unroll
        for (int mt = 0; mt < 4; ++mt) {
            int ro = (wm + mt * 16 + col15) * SA1_PITCH + k0 + quad * 8;
            ah[mt] = *(const s16x8*)&sAh[ro];
            al[mt] = *(const s16x8*)&sAl[ro];
        }
#pragma unroll
        for (int ot = 0; ot < 4; ++ot) {
            int orow = wo + ot * 16 + col15;
            if (orow < Ov && k0 + quad * 8 < CPWv) {
                size_t go = (size_t)orow * CPWv + k0 + quad * 8;
                bh[ot] = *(const s16x8*)(Bh + go);
                bl[ot] = *(const s16x8*)(Bl + go);
            } else {
                bh[ot] = {0, 0, 0, 0, 0, 0, 0, 0};
                bl[ot] = {0, 0, 0, 0, 0, 0, 0, 0};
            }
        }
#pragma unroll
        for (int mt = 0; mt < 4; ++mt)
#pragma unroll
            for (int ot = 0; ot < 4; ++ot) {
                acc[mt][ot] = __builtin_amdgcn_mfma_f32_16x16x32_bf16(
                    ah[mt], bl[ot], acc[mt][ot], 0, 0, 0);
                acc[mt][ot] = __builtin_amdgcn_mfma_f32_16x16x32_bf16(
                    al[mt], bh[ot], acc[mt][ot], 0, 0, 0);
                acc[mt][ot] = __builtin_amdgcn_mfma_f32_16x16x32_bf16(
                    ah[mt], bh[ot], acc[mt][ot], 0, 0, 0);
            }
    }
}

__device__ __forceinline__ void sa1_stage_x(
    unsigned short* sAh, unsigned short* sAl,
    const float* __restrict__ XG, int m0, int lr, int lc)
{
    __syncthreads();
#pragma unroll
    for (int it = 0; it < 2; ++it) {
        int r = lr + it * 64;
        unsigned short h[8], l[8];
        if (lc == 0) {   // AC=8: cols 0..7 data, 8..31 zero
            const float* xr = XG + (size_t)(m0 + r) * 8;
            float4 v0 = *(const float4*)xr;
            float4 v1 = *(const float4*)(xr + 4);
            float vv[8] = {v0.x, v0.y, v0.z, v0.w, v1.x, v1.y, v1.z, v1.w};
#pragma unroll
            for (int j = 0; j < 8; ++j) f2bf_split(vv[j], h[j], l[j]);
        } else {
#pragma unroll
            for (int j = 0; j < 8; ++j) { h[j] = 0; l[j] = 0; }
        }
        *(ushort4*)&sAh[r * SA1_PITCH + lc]     = make_ushort4(h[0], h[1], h[2], h[3]);
        *(ushort4*)&sAh[r * SA1_PITCH + lc + 4] = make_ushort4(h[4], h[5], h[6], h[7]);
        *(ushort4*)&sAl[r * SA1_PITCH + lc]     = make_ushort4(l[0], l[1], l[2], l[3]);
        *(ushort4*)&sAl[r * SA1_PITCH + lc + 4] = make_ushort4(l[4], l[5], l[6], l[7]);
    }
    __syncthreads();
}

__device__ __forceinline__ void sa1_stage_act(
    unsigned short* sAh, unsigned short* sAl, const f32x4 (&acc)[4][4],
    const float* __restrict__ sc, const float* __restrict__ sh,
    int wm, int wo, int col15, int quad)
{
    __syncthreads();
    if (wo == 0) {   // prev-layer O=64 -> only wid 0,2 hold valid cols
#pragma unroll
        for (int ot = 0; ot < 4; ++ot) {
            int c = ot * 16 + col15;
            float s = sc[c], b = sh[c];
#pragma unroll
            for (int mt = 0; mt < 4; ++mt)
#pragma unroll
                for (int r = 0; r < 4; ++r) {
                    int m = wm + mt * 16 + quad * 4 + r;
                    float v = fmaxf(acc[mt][ot][r] * s + b, 0.f);
                    unsigned short hh, ll;
                    f2bf_split(v, hh, ll);
                    sAh[m * SA1_PITCH + c] = hh;
                    sAl[m * SA1_PITCH + c] = ll;
                }
        }
    }
    __syncthreads();
}

__device__ __forceinline__ void sa1_stats(
    const f32x4 (&a0)[4][4], const f32x4 (&a1)[4][4], float* sred,
    double* __restrict__ part, int Ov, int bx, int tid, int wid,
    int quad, int col15)
{
#pragma unroll
    for (int ot = 0; ot < 4; ++ot) {
        float s = 0.f, s2 = 0.f;
#pragma unroll
        for (int mt = 0; mt < 4; ++mt)
#pragma unroll
            for (int r = 0; r < 4; ++r) { float v = a0[mt][ot][r]; s += v; s2 += v * v; }
#pragma unroll
        for (int mt = 0; mt < 4; ++mt)
#pragma unroll
            for (int r = 0; r < 4; ++r) { float v = a1[mt][ot][r]; s += v; s2 += v * v; }
        int slot = ((wid * 4 + quad) * 16 + col15) * 4 + ot;
        sred[slot * 2] = s;
        sred[slot * 2 + 1] = s2;
    }
    __syncthreads();
    if (tid < 128) {
        int col = tid, o = col;
        if (o < Ov) {
            int cb = col >> 6, ot = (col & 63) >> 4, c15 = col & 15;
            double S = 0.0, S2 = 0.0;
#pragma unroll
            for (int wp = 0; wp < 2; ++wp) {
                int wd = cb + wp * 2;
#pragma unroll
                for (int q = 0; q < 4; ++q) {
                    int slot = ((wd * 4 + q) * 16 + c15) * 4 + ot;
                    S += (double)sred[slot * 2];
                    S2 += (double)sred[slot * 2 + 1];
                }
            }
            part[(size_t)o * 512 + bx] = S;
            part[(size_t)Ov * 512 + (size_t)o * 512 + bx] = S2;
        }
    }
}

__device__ __forceinline__ void sa1_finalize(
    const double* __restrict__ part, int Ov, const float* __restrict__ gl,
    const float* __restrict__ bbl, float* __restrict__ scl,
    float* __restrict__ shl, double* sd, int bx, int tid)
{
    if (bx < Ov) {
        double s  = part[(size_t)bx * 512 + tid] + part[(size_t)bx * 512 + 256 + tid];
        size_t b2 = (size_t)Ov * 512 + (size_t)bx * 512;
        double s2 = part[b2 + tid] + part[b2 + 256 + tid];
        sd[tid] = s;
        sd[256 + tid] = s2;
        __syncthreads();
#pragma unroll
        for (int st = 128; st > 0; st >>= 1) {
            if (tid < st) {
                sd[tid] += sd[tid + st];
                sd[256 + tid] += sd[256 + tid + st];
            }
            __syncthreads();
        }
        if (tid == 0) {
            double mean = sd[0] * (1.0 / 131072.0);
            double var = sd[256] * (1.0 / 131072.0) - mean * mean;
            float varf = (float)var;
            if (varf < 0.f) varf = 0.f;
            float sc = gl[bx] * rsqrtf(varf + 1e-5f);
            scl[bx] = sc;
            shl[bx] = bbl[bx] - (float)mean * sc;
        }
    }
}

__device__ __forceinline__ void sa1_epi(
    const f32x4 (&acc)[4][4], const float* __restrict__ sc2,
    const float* __restrict__ sh2, float* __restrict__ feat1,
    int tile, int wm, int wo, int col15, int quad)
{
#pragma unroll
    for (int ot = 0; ot < 4; ++ot) {
        int og = wo + ot * 16 + col15;
        float s = sc2[og], b = sh2[og];
        float m01 = 0.f, m23 = 0.f;
#pragma unroll
        for (int r = 0; r < 4; ++r) {
            m01 = fmaxf(m01, fmaxf(acc[0][ot][r] * s + b, 0.f));
            m01 = fmaxf(m01, fmaxf(acc[1][ot][r] * s + b, 0.f));
            m23 = fmaxf(m23, fmaxf(acc[2][ot][r] * s + b, 0.f));
            m23 = fmaxf(m23, fmaxf(acc[3][ot][r] * s + b, 0.f));
        }
        m01 = fmaxf(m01, __shfl_xor(m01, 16));
        m01 = fmaxf(m01, __shfl_xor(m01, 32));
        m23 = fmaxf(m23, __shfl_xor(m23, 16));
        m23 = fmaxf(m23, __shfl_xor(m23, 32));
        if (quad == 0) {
            int cb = tile * 4 + (wm >> 5);
            feat1[(size_t)cb * 128 + og] = m01;
            feat1[(size_t)(cb + 1) * 128 + og] = m23;
        }
    }
}

__global__ __launch_bounds__(256, 2) void sa1_fused(
    const float* __restrict__ XG,
    const unsigned short* __restrict__ WH0, const unsigned short* __restrict__ WL0,
    const unsigned short* __restrict__ WH1, const unsigned short* __restrict__ WL1,
    const unsigned short* __restrict__ WH2, const unsigned short* __restrict__ WL2,
    const float* __restrict__ g0, const float* __restrict__ b0,
    const float* __restrict__ g1, const float* __restrict__ b1,
    const float* __restrict__ g2, const float* __restrict__ b2,
    double* __restrict__ part, float* __restrict__ scales,
    float* __restrict__ shifts, float* __restrict__ feat1)
{
    __shared__ __align__(16) unsigned short sAh[128 * SA1_PITCH];
    __shared__ __align__(16) unsigned short sAl[128 * SA1_PITCH];
    __shared__ __align__(16) float sred[2048];
    cg::grid_group grid = cg::this_grid();

    const int tid = threadIdx.x;
    const int lane = tid & 63;
    const int wid = tid >> 6;
    const int col15 = lane & 15;
    const int quad = lane >> 4;
    const int wm = (wid >> 1) * 64;
    const int wo = (wid & 1) * 64;
    const int bx = blockIdx.x;
    const int lr = tid >> 2;
    const int lc = (tid & 3) * 8;
    const int m0t0 = bx * 128, m0t1 = (bx + 512) * 128;

    f32x4 a0t0[4][4], a0t1[4][4], a1t0[4][4], a1t1[4][4], a2t0[4][4], a2t1[4][4];

    // ---- layer 0: AC=8 (CPW=8), O=64 ----
    sa1_stage_x(sAh, sAl, XG, m0t0, lr, lc);
    sa1_gemm<1, 8, 64>(a0t0, sAh, sAl, WH0, WL0, wm, wo, col15, quad);
    sa1_stage_x(sAh, sAl, XG, m0t1, lr, lc);
    sa1_gemm<1, 8, 64>(a0t1, sAh, sAl, WH0, WL0, wm, wo, col15, quad);
    sa1_stats(a0t0, a0t1, sred, part, 64, bx, tid, wid, quad, col15);
    __threadfence();
    grid.sync();
    sa1_finalize(part, 64, g0, b0, scales + 0, shifts + 0, (double*)sred, bx, tid);
    __threadfence();
    grid.sync();

    // ---- layer 1: K=64, O=64 ----
    sa1_stage_act(sAh, sAl, a0t0, scales + 0, shifts + 0, wm, wo, col15, quad);
    sa1_gemm<2, 64, 64>(a1t0, sAh, sAl, WH1, WL1, wm, wo, col15, quad);
    sa1_stage_act(sAh, sAl, a0t1, scales + 0, shifts + 0, wm, wo, col15, quad);
    sa1_gemm<2, 64, 64>(a1t1, sAh, sAl, WH1, WL1, wm, wo, col15, quad);
    sa1_stats(a1t0, a1t1, sred, part, 64, bx, tid, wid, quad, col15);
    __threadfence();
    grid.sync();
    sa1_finalize(part, 64, g1, b1, scales + 1024, shifts + 1024, (double*)sred, bx, tid);
    __threadfence();
    grid.sync();

    // ---- layer 2: K=64, O=128 ----
    sa1_stage_act(sAh, sAl, a1t0, scales + 1024, shifts + 1024, wm, wo, col15, quad);
    sa1_gemm<2, 64, 128>(a2t0, sAh, sAl, WH2, WL2, wm, wo, col15, quad);
    sa1_stage_act(sAh, sAl, a1t1, scales + 1024, shifts + 1024, wm, wo, col15, quad);
    sa1_gemm<2, 64, 128>(a2t1, sAh, sAl, WH2, WL2, wm, wo, col15, quad);
    sa1_stats(a2t0, a2t1, sred, part, 128, bx, tid, wid, quad, col15);
    __threadfence();
    grid.sync();
    sa1_finalize(part, 128, g2, b2, scales + 2048, shifts + 2048, (double*)sred, bx, tid);
    __threadfence();
    grid.sync();

    // ---- epilogue: BN + ReLU + max over K=32 -> feat1 (4096,128) ----
    sa1_epi(a2t0, scales + 2048, shifts + 2048, feat1, bx, wm, wo, col15, quad);
    sa1_epi(a2t1, scales + 2048, shifts + 2048, feat1, bx + 512, wm, wo, col15, quad);
}

// ---------------- fused GEMM: Y = act(X) * W^T  (+ BN stats) ---------------
// (unchanged R13 structure; used for SA2/SA3 and the SA1 fallback path)
__global__ __launch_bounds__(256) void gemm_fused(
    const float* __restrict__ X,
    const float* __restrict__ scale, const float* __restrict__ shift,
    int applyAct,
    const unsigned short* __restrict__ Bh, const unsigned short* __restrict__ Bl,
    float* __restrict__ Y, double* __restrict__ part,
    int M, int AC, int CPW, int O, int YBmain)
{
    constexpr int PITCH = 40;
    __shared__ __align__(16) unsigned short sAh[128 * PITCH];
    __shared__ __align__(16) unsigned short sAl[128 * PITCH];
    __shared__ __align__(16) unsigned short sBh[128 * PITCH];
    __shared__ __align__(16) unsigned short sBl[128 * PITCH];
    __shared__ float sred[2048];

    const int tid = threadIdx.x;
    const int lane = tid & 63;
    const int wid = tid >> 6;
    const int col15 = lane & 15;
    const int quad = lane >> 4;
    const int wm = (wid >> 1) * 64;
    const int wo = (wid & 1) * 64;
    const int m0 = blockIdx.x * 128;
    const int o0 = blockIdx.y * 128;
    const int YB = YBmain;
    const int lr = tid >> 2;
    const int lc = (tid & 3) * 8;

    f32x4 acc[4][4];
#pragma unroll
    for (int mt = 0; mt < 4; ++mt)
#pragma unroll
        for (int ot = 0; ot < 4; ++ot)
            acc[mt][ot] = {0.f, 0.f, 0.f, 0.f};

    for (int k0 = 0; k0 < CPW; k0 += 32) {
#pragma unroll
        for (int it = 0; it < 2; ++it) {
            int r = lr + it * 64;
            int c = k0 + lc;
            unsigned short h[8], l[8];
            if (c + 8 <= AC) {
                const float* xr = X + (size_t)(m0 + r) * AC + c;
                float4 v0 = *(const float4*)xr;
                float4 v1 = *(const float4*)(xr + 4);
                float vv[8] = {v0.x, v0.y, v0.z, v0.w, v1.x, v1.y, v1.z, v1.w};
#pragma unroll
                for (int j = 0; j < 8; ++j) {
                    float v = vv[j];
                    if (applyAct) v = fmaxf(v * scale[c + j] + shift[c + j], 0.f);
                    f2bf_split(v, h[j], l[j]);
                }
            } else {
#pragma unroll
                for (int j = 0; j < 8; ++j) { h[j] = 0; l[j] = 0; }
            }
            *(ushort4*)&sAh[r * PITCH + lc] = make_ushort4(h[0], h[1], h[2], h[3]);
            *(ushort4*)&sAh[r * PITCH + lc + 4] = make_ushort4(h[4], h[5], h[6], h[7]);
            *(ushort4*)&sAl[r * PITCH + lc] = make_ushort4(l[0], l[1], l[2], l[3]);
            *(ushort4*)&sAl[r * PITCH + lc + 4] = make_ushort4(l[4], l[5], l[6], l[7]);
        }
#pragma unroll
        for (int it = 0; it < 2; ++it) {
            int r = lr + it * 64;
            int c = k0 + lc;
            int o = o0 + r;
            uint4 vh = {0, 0, 0, 0}, vl = {0, 0, 0, 0};
            if (o < O && c < CPW) {
                size_t goff = (size_t)o * CPW + c;
                vh = *(const uint4*)(Bh + goff);
                vl = *(const uint4*)(Bl + goff);
            }
            *(uint4*)&sBh[r * PITCH + lc] = vh;
            *(uint4*)&sBl[r * PITCH + lc] = vl;
        }
        __syncthreads();
        s16x8 ah[4], al[4], bh[4], bl[4];
#pragma unroll
        for (int mt = 0; mt < 4; ++mt) {
            int rowoff = (wm + mt * 16 + col15) * PITCH + quad * 8;
            ah[mt] = *(const s16x8*)&sAh[rowoff];
            al[mt] = *(const s16x8*)&sAl[rowoff];
        }
#pragma unroll
        for (int ot = 0; ot < 4; ++ot) {
            int rowoff = (wo + ot * 16 + col15) * PITCH + quad * 8;
            bh[ot] = *(const s16x8*)&sBh[rowoff];
            bl[ot] = *(const s16x8*)&sBl[rowoff];
        }
#pragma unroll
        for (int mt = 0; mt < 4; ++mt)
#pragma unroll
            for (int ot = 0; ot < 4; ++ot) {
                acc[mt][ot] = __builtin_amdgcn_mfma_f32_16x16x32_bf16(
                    ah[mt], bl[ot], acc[mt][ot], 0, 0, 0);
                acc[mt][ot] = __builtin_amdgcn_mfma_f32_16x16x32_bf16(
                    al[mt], bh[ot], acc[mt][ot], 0, 0, 0);
                acc[mt][ot] = __builtin_amdgcn_mfma_f32_16x16x32_bf16(
                    ah[mt], bh[ot], acc[mt][ot], 0, 0, 0);
            }
        __syncthreads();
    }
#pragma unroll
    for (int mt = 0; mt < 4; ++mt)
#pragma unroll
        for (int ot = 0; ot < 4; ++ot) {
            int og = o0 + wo + ot * 16 + col15;
            if (og < O) {
#pragma unroll
                for (int r = 0; r < 4; ++r) {
                    int mg = m0 + wm + mt * 16 + quad * 4 + r;
                    Y[(size_t)mg * O + og] = acc[mt][ot][r];
                }
            }
        }
    // BN stats epilogue (deterministic fixed-order combine).
#pragma unroll
    for (int ot = 0; ot < 4; ++ot) {
        float s = 0.f, s2 = 0.f;
#pragma unroll
        for (int mt = 0; mt < 4; ++mt)
#pragma unroll
            for (int r = 0; r < 4; ++r) {
                float v = acc[mt][ot][r];
                s += v;
                s2 += v * v;
            }
        int slot = ((wid * 4 + quad) * 16 + col15) * 4 + ot;
        sred[slot * 2] = s;
        sred[slot * 2 + 1] = s2;
    }
    __syncthreads();
    if (tid < 128) {
        int col = tid;
        int o = o0 + col;
        if (o < O) {
            int cb = col >> 6;
            int ot = (col & 63) >> 4;
            int c15 = col & 15;
            double S = 0.0, S2 = 0.0;
#pragma unroll
            for (int wp = 0; wp < 2; ++wp) {
                int wd = cb + wp * 2;
#pragma unroll
                for (int q = 0; q < 4; ++q) {
                    int slot = ((wd * 4 + q) * 16 + c15) * 4 + ot;
                    S += (double)sred[slot * 2];
                    S2 += (double)sred[slot * 2 + 1];
                }
            }
            part[(size_t)o * YB + blockIdx.x] = S;
            part[(size_t)O * YB + (size_t)o * YB + blockIdx.x] = S2;
        }
    }
}

// ---------------- finalize BN: one block per channel ----------------
__global__ __launch_bounds__(256) void finalize_bn(
    const double* __restrict__ part, const float* __restrict__ g,
    const float* __restrict__ bb, float* __restrict__ scale,
    float* __restrict__ shift, int O, int YB, double invM)
{
    int o = blockIdx.x;
    int tid = threadIdx.x;
    double s = 0.0, s2 = 0.0;
    for (int yb = tid; yb < YB; yb += 256) {
        s  += part[(size_t)o * YB + yb];
        s2 += part[(size_t)O * YB + (size_t)o * YB + yb];
    }
    __shared__ double sd[512];
    sd[tid] = s;
    sd[256 + tid] = s2;
    __syncthreads();
#pragma unroll
    for (int st = 128; st > 0; st >>= 1) {
        if (tid < st) {
            sd[tid] += sd[tid + st];
            sd[256 + tid] += sd[256 + tid + st];
        }
        __syncthreads();
    }
    if (tid == 0) {
        double mean = sd[0] * invM;
        double var = sd[256] * invM - mean * mean;
        float varf = (float)var;
        if (varf < 0.f) varf = 0.f;
        float sc = g[o] * rsqrtf(varf + 1e-5f);
        scale[o] = sc;
        shift[o] = bb[o] - (float)mean * sc;
    }
}

// ---------------- BN + ReLU + max over K ----------------
__global__ __launch_bounds__(256) void bn_relu_max(
    const float* __restrict__ Y, const float* __restrict__ scale,
    const float* __restrict__ shift, float* __restrict__ out,
    int Stot, int K, int O)
{
    int idx = blockIdx.x * 256 + threadIdx.x;
    if (idx >= Stot * O) return;
    int s = idx / O;
    int o = idx - s * O;
    const float* base = Y + (size_t)s * K * O + o;
    float sc = scale[o], sh = shift[o];
    float mx = 0.f;
    for (int k = 0; k < K; ++k) {
        float v = base[(size_t)k * O] * sc + sh;
        v = fmaxf(v, 0.f);
        mx = fmaxf(mx, v);
    }
    out[idx] = mx;
}

// ============================================================================
extern "C" void kernel_launch(void* const* d_in, const int* in_sizes, int n_in,
                              void* d_out, int out_size, void* d_ws, size_t ws_size,
                              hipStream_t stream)
{
    const float* xin = (const float*)d_in[0];
    const float* w[9]; const float* g[9]; const float* bb[9];
    for (int i = 0; i < 9; ++i) {
        w[i]  = (const float*)d_in[1 + 3 * i];
        g[i]  = (const float*)d_in[2 + 3 * i];
        bb[i] = (const float*)d_in[3 + 3 * i];
    }

    char* base = (char*)d_ws;
    size_t off = 0;
    auto alloc = [&](size_t bytes) -> void* {
        void* p = base + off;
        off = (off + bytes + 255) & ~(size_t)255;
        return p;
    };
    const int OC[9][3] = {{64,4,8},{64,64,64},{128,64,64},
                          {128,131,136},{128,128,128},{256,128,128},
                          {256,259,264},{512,256,256},{1024,512,512}};
    size_t woff[10]; woff[0] = 0;
    for (int i = 0; i < 9; ++i) woff[i + 1] = woff[i] + (size_t)OC[i][0] * OC[i][2];

    // --- small / metadata region (memset-protected) ---
    int*    fps1   = (int*)alloc((size_t)4096 * 4);
    int*    fps2   = (int*)alloc((size_t)1024 * 4);
    int*    qb2    = (int*)alloc((size_t)65536 * 4);
    float*  nx1    = (float*)alloc((size_t)12288 * 4);
    float*  nx2    = (float*)alloc((size_t)3072 * 4);
    float*  feat1  = (float*)alloc((size_t)524288 * 4);
    float*  feat2  = (float*)alloc((size_t)262144 * 4);
    double* part   = (double*)alloc((size_t)262144 * 8);
    float*  scales = (float*)alloc((size_t)9 * 1024 * 4);
    float*  shifts = (float*)alloc((size_t)9 * 1024 * 4);
    unsigned short* WH = (unsigned short*)alloc(woff[9] * 2);
    unsigned short* WL = (unsigned short*)alloc(woff[9] * 2);
    const size_t zeroBytes = off;
    // --- big ping/pong buffers ---
    float*  XG = (float*)alloc((size_t)65536 * 136 * 4);
    float*  A  = (float*)alloc((size_t)16777216 * 4);
    if (off > ws_size) return;

    hipMemsetAsync(d_ws, 0, zeroBytes, stream);

    PWArgs pwa;
    for (int i = 0; i < 9; ++i) {
        pwa.w[i] = w[i]; pwa.off[i] = (unsigned)woff[i];
        pwa.O[i] = OC[i][0]; pwa.C[i] = OC[i][1]; pwa.CP[i] = OC[i][2];
    }
    const int nPrep = (int)((woff[9] + 255) / 256);

    // ---------------- SA1 ----------------
    fps_block<256, 16, 4><<<8 + nPrep, 256, 0, stream>>>(
        xin, 512, fps1, nx1, 8, pwa, WH, WL, (int)woff[9]);
    // qb_group1 blocks 0-1023: group; 1024-1031: SA2 single-wave FPS
    // (input nx1 ready; outputs fps2/nx2 consumed after stream-ordered later).
    qb_group1<<<1024 + 8, 256, 0, stream>>>(xin, nx1, XG, 1024, nx1, fps2, nx2);

    // SA1 MLP: cooperative fused kernel (fallback: R13 dispatch chain).
    {
        const float* aXG = XG;
        const unsigned short* wh0 = WH + woff[0]; const unsigned short* wl0 = WL + woff[0];
        const unsigned short* wh1 = WH + woff[1]; const unsigned short* wl1 = WL + woff[1];
        const unsigned short* wh2 = WH + woff[2]; const unsigned short* wl2 = WL + woff[2];
        const float* ag0 = g[0]; const float* ab0 = bb[0];
        const float* ag1 = g[1]; const float* ab1 = bb[1];
        const float* ag2 = g[2]; const float* ab2 = bb[2];
        double* apart = part; float* ascales = scales; float* ashifts = shifts;
        float* afeat1 = feat1;
        void* kargs[] = {
            (void*)&aXG, (void*)&wh0, (void*)&wl0, (void*)&wh1, (void*)&wl1,
            (void*)&wh2, (void*)&wl2, (void*)&ag0, (void*)&ab0, (void*)&ag1,
            (void*)&ab1, (void*)&ag2, (void*)&ab2, (void*)&apart,
            (void*)&ascales, (void*)&ashifts, (void*)&afeat1
        };
        hipError_t ce = hipLaunchCooperativeKernel(
            (const void*)sa1_fused, dim3(512), dim3(256), kargs, 0, stream);
        if (ce != hipSuccess) {
            // Fallback: R13 serial chain (correct, ~previous perf).
            gemm_fused<<<dim3(1024, 1), 256, 0, stream>>>(XG, nullptr, nullptr, 0, WH + woff[0], WL + woff[0], A, part, 131072, 8, 8, 64, 1024);
            finalize_bn<<<64, 256, 0, stream>>>(part, g[0], bb[0], scales + 0 * 1024, shifts + 0 * 1024, 64, 1024, 1.0 / 131072.0);
            gemm_fused<<<dim3(1024, 1), 256, 0, stream>>>(A, scales + 0 * 1024, shifts + 0 * 1024, 1, WH + woff[1], WL + woff[1], XG, part, 131072, 64, 64, 64, 1024);
            finalize_bn<<<64, 256, 0, stream>>>(part, g[1], bb[1], scales + 1 * 1024, shifts + 1 * 1024, 64, 1024, 1.0 / 131072.0);
            gemm_fused<<<dim3(1024, 1), 256, 0, stream>>>(XG, scales + 1 * 1024, shifts + 1 * 1024, 1, WH + woff[2], WL + woff[2], A, part, 131072, 64, 64, 128, 1024);
            finalize_bn<<<128, 256, 0, stream>>>(part, g[2], bb[2], scales + 2 * 1024, shifts + 2 * 1024, 128, 1024, 1.0 / 131072.0);
            bn_relu_max<<<(4096 * 128) / 256, 256, 0, stream>>>(A, scales + 2 * 1024, shifts + 2 * 1024, feat1, 4096, 32, 128);
        }
    }

    // ---------------- SA2 ----------------
    query_ball_kernel<<<(8 * 128 * 64) / 256, 256, 0, stream>>>(
        nx1, 3, 512, nx2, 8 * 128, 128, 0.16f, 64, qb2);
    group2_kernel<<<(65536 * 136) / 256, 256, 0, stream>>>(nx1, feat1, qb2, nx2, XG);

    // L2_0: (65536, AC=136) -> 128
    gemm_fused<<<dim3(512, 1), 256, 0, stream>>>(XG, nullptr, nullptr, 0, WH + woff[3], WL + woff[3], A, part, 65536, 136, 136, 128, 512);
    finalize_bn<<<128, 256, 0, stream>>>(part, g[3], bb[3], scales + 3 * 1024, shifts + 3 * 1024, 128, 512, 1.0 / 65536.0);
    // L2_1: 128 -> 128
    gemm_fused<<<dim3(512, 1), 256, 0, stream>>>(A, scales + 3 * 1024, shifts + 3 * 1024, 1, WH + woff[4], WL + woff[4], XG, part, 65536, 128, 128, 128, 512);
    finalize_bn<<<128, 256, 0, stream>>>(part, g[4], bb[4], scales + 4 * 1024, shifts + 4 * 1024, 128, 512, 1.0 / 65536.0);
    // L2_2: 128 -> 256
    gemm_fused<<<dim3(512, 2), 256, 0, stream>>>(XG, scales + 4 * 1024, shifts + 4 * 1024, 1, WH + woff[5], WL + woff[5], A, part, 65536, 128, 128, 256, 512);
    finalize_bn<<<256, 256, 0, stream>>>(part, g[5], bb[5], scales + 5 * 1024, shifts + 5 * 1024, 256, 512, 1.0 / 65536.0);
    bn_relu_max<<<(1024 * 256) / 256, 256, 0, stream>>>(A, scales + 5 * 1024, shifts + 5 * 1024, feat2, 1024, 64, 256);

    // ---------------- SA3 (group_all) ----------------
    group3_kernel<<<(1024 * 264) / 256, 256, 0, stream>>>(nx2, feat2, XG);

    // L3_0: (1024, AC=264) -> 256
    gemm_fused<<<dim3(8, 2), 256, 0, stream>>>(XG, nullptr, nullptr, 0, WH + woff[6], WL + woff[6], A, part, 1024, 264, 264, 256, 8);
    finalize_bn<<<256, 256, 0, stream>>>(part, g[6], bb[6], scales + 6 * 1024, shifts + 6 * 1024, 256, 8, 1.0 / 1024.0);
    // L3_1: 256 -> 512
    gemm_fused<<<dim3(8, 4), 256, 0, stream>>>(A, scales + 6 * 1024, shifts + 6 * 1024, 1, WH + woff[7], WL + woff[7], XG, part, 1024, 256, 256, 512, 8);
    finalize_bn<<<512, 256, 0, stream>>>(part, g[7], bb[7], scales + 7 * 1024, shifts + 7 * 1024, 512, 8, 1.0 / 1024.0);
    // L3_2: 512 -> 1024
    gemm_fused<<<dim3(8, 8), 256, 0, stream>>>(XG, scales + 7 * 1024, shifts + 7 * 1024, 1, WH + woff[8], WL + woff[8], A, part, 1024, 512, 512, 1024, 8);
    finalize_bn<<<1024, 256, 0, stream>>>(part, g[8], bb[8], scales + 8 * 1024, shifts + 8 * 1024, 1024, 8, 1.0 / 1024.0);
    bn_relu_max<<<(8 * 1024) / 256, 256, 0, stream>>>(A, scales + 8 * 1024, shifts + 8 * 1024, (float*)d_out, 8, 128, 1024);
}

// Round 6
// 932.318 us; speedup vs baseline: 1.4847x; 1.4847x over previous
//
#include <hip/hip_runtime.h>
#include <hip/hip_cooperative_groups.h>

namespace cg = cooperative_groups;

// ============================================================================
// TemporalPointNet (PointNet++ style) forward on MI355X.
// B=2, T=4 -> BT=8 "batches", N=4096 points, 4 coords (xyz + t).
// SA1: npoint=512, r=0.2, K=32, C_in=4,  MLP 64,64,128
// SA2: npoint=128, r=0.4, K=64, C_in=131, MLP 128,128,256
// SA3: group_all,          K=128, C_in=259, MLP 256,512,1024
//
// R17 == R16 resubmit (R16's bench was lost to an infra failure: "container
// failed twice", no pytest/profile output). R16 audit found no hang path:
// coop launch validates occupancy (errors, never deadlocks), mlp_coop has no
// early return before any grid.sync, R14 proved coop-under-capture works.
//
// R16 changes vs R15 (both kept):
//  (1) FALLBACK BUG FIX: R15's fallback gemm_fused ignored blockIdx.y ->
//      for OB>1 launches (L2_2, all SA3) half+ of tiles never computed ->
//      stale part -> var~0 -> scale ~316 -> absmax 4e5. Fixed via
//      tstart = blockIdx.x + blockIdx.y*gridDim.x (one tile/block, R13-exact).
//  (2) Trailing __syncthreads in mlp_layer tile loop: protects sred reads
//      (tid<128 part-write) from the next tile's sred writes when G < ntile
//      (a coop-path race in R15).
//  (3) Coop grid from hipOccupancyMaxActiveBlocksPerMultiprocessor (clamped
//      to 512); query fail -> skip coop. All mlp_coop phases grid-stride.
//  Both paths produce bit-identical R13 math; profile kernel names show
//  which ran. FPS critical chains byte-identical to R11/R13 (286us best).
// ============================================================================

typedef short s16x8 __attribute__((ext_vector_type(8)));
typedef float f32x4 __attribute__((ext_vector_type(4)));

__device__ __forceinline__ unsigned short f2bf_rne(float f) {
    unsigned u = __float_as_uint(f);
    u += 0x7FFFu + ((u >> 16) & 1u);
    return (unsigned short)(u >> 16);
}
// split f32 -> (hi, lo) bf16 pair: hi = rne(v), lo = rne(v - hi)
__device__ __forceinline__ void f2bf_split(float v, unsigned short& hi,
                                           unsigned short& lo) {
    unsigned u = __float_as_uint(v);
    unsigned r = u + 0x7FFFu + ((u >> 16) & 1u);
    hi = (unsigned short)(r >> 16);
    float vh = __uint_as_float(r & 0xFFFF0000u);
    lo = f2bf_rne(v - vh);
}

__device__ __forceinline__ unsigned long long umax64(unsigned long long a,
                                                     unsigned long long b) {
    return a > b ? a : b;
}

// Wave64 max-reduce via DPP: 1 DPP + 1 max per step (R9 measured-best).
__device__ __forceinline__ unsigned wred_umax63(unsigned v) {
    unsigned t;
    t = (unsigned)__builtin_amdgcn_update_dpp(0, (int)v, 0x111, 0xf, 0xf, true); if (t > v) v = t;
    t = (unsigned)__builtin_amdgcn_update_dpp(0, (int)v, 0x112, 0xf, 0xf, true); if (t > v) v = t;
    t = (unsigned)__builtin_amdgcn_update_dpp(0, (int)v, 0x114, 0xf, 0xf, true); if (t > v) v = t;
    t = (unsigned)__builtin_amdgcn_update_dpp(0, (int)v, 0x118, 0xf, 0xf, true); if (t > v) v = t;
    t = (unsigned)__builtin_amdgcn_update_dpp(0, (int)v, 0x142, 0xa, 0xf, true); if (t > v) v = t;
    t = (unsigned)__builtin_amdgcn_update_dpp(0, (int)v, 0x143, 0xc, 0xf, true); if (t > v) v = t;
    return v;
}

// Wave argmax of (dist, min-index). Exact first-occurrence argmax.
__device__ __forceinline__ void wave_argmax(unsigned dbits, unsigned nInv,
                                            unsigned& vmax, unsigned& iInv) {
    unsigned m = wred_umax63(dbits);
    vmax = (unsigned)__builtin_amdgcn_readlane((int)m, 63);
    unsigned cand = (dbits == vmax) ? nInv : 0u;
    unsigned im = wred_umax63(cand);
    iInv = (unsigned)__builtin_amdgcn_readlane((int)im, 63);
}

// ---------------- all-layer weight pre-split (device body) ----------------
struct PWArgs {
    const float* w[9];
    unsigned off[9];
    int O[9], C[9], CP[9];
};
__device__ __forceinline__ void prep_w_dev(const PWArgs& a,
                                           unsigned short* __restrict__ wh,
                                           unsigned short* __restrict__ wl,
                                           int i) {
    int l = 0;
#pragma unroll
    for (int k = 1; k < 9; ++k) if (i >= (int)a.off[k]) l = k;
    int li = i - (int)a.off[l];
    int CP = a.CP[l];
    int o = li / CP;
    int c = li - o * CP;
    float v = (c < a.C[l]) ? a.w[l][(size_t)o * a.C[l] + c] : 0.f;
    unsigned short h, lo;
    f2bf_split(v, h, lo);
    wh[i] = h; wl[i] = lo;
}

// ---------------- FPS (multi-wave): one block (NT thr) per batch ------------
// R7/R9 structure (measured best 286us). Blocks >= nFps run the weight
// pre-split (fully hidden in the FPS shadow).
template<int NT, int ITEMS, int STRIDE>
__global__ __launch_bounds__(NT) void fps_block(
    const float* __restrict__ pts, int npoint,
    int* __restrict__ outIdx, float* __restrict__ outXyz,
    int nFps, PWArgs pw, unsigned short* __restrict__ wh,
    unsigned short* __restrict__ wl, int wtotal)
{
    constexpr int N = NT * ITEMS;
    constexpr int NW = NT / 64;
    __shared__ float4 scoord[N];
    __shared__ unsigned long long wkey[2][NW];

    if (blockIdx.x >= nFps) {   // piggyback: weight split on idle CUs
        int i = (blockIdx.x - nFps) * NT + threadIdx.x;
        if (i < wtotal) prep_w_dev(pw, wh, wl, i);
        return;
    }

    const int b = blockIdx.x;
    const int tid = threadIdx.x;
    const int wid = tid >> 6;
    const int lane = tid & 63;
    const float* P = pts + (size_t)b * N * STRIDE;

    float px[ITEMS], py[ITEMS], pz[ITEMS], dloc[ITEMS];
#pragma unroll
    for (int w = 0; w < ITEMS; ++w) {
        int n = tid + w * NT;
        float x, y, z;
        if (STRIDE == 4) {
            float4 v = *(const float4*)(P + (size_t)n * 4);
            x = v.x; y = v.y; z = v.z;
        } else {
            x = P[(size_t)n * STRIDE + 0];
            y = P[(size_t)n * STRIDE + 1];
            z = P[(size_t)n * STRIDE + 2];
        }
        px[w] = x; py[w] = y; pz[w] = z;
        scoord[n] = make_float4(x, y, z, 0.f);
        dloc[w] = 1e10f;
    }
    __syncthreads();
    float4 c0 = scoord[0];
    float cx = c0.x, cy = c0.y, cz = c0.z;
    int far = 0;

    for (int i = 0; i < npoint; ++i) {
        if (tid == 0) {
            outIdx[(size_t)b * npoint + i] = far;
            outXyz[((size_t)b * npoint + i) * 3 + 0] = cx;
            outXyz[((size_t)b * npoint + i) * 3 + 1] = cy;
            outXyz[((size_t)b * npoint + i) * 3 + 2] = cz;
        }
        float bestV = -1.0f;
        int bestW = 0;
#pragma unroll
        for (int w = 0; w < ITEMS; ++w) {
            float dx = __fsub_rn(px[w], cx);
            float dy = __fsub_rn(py[w], cy);
            float dz = __fsub_rn(pz[w], cz);
            float d = __fadd_rn(__fadd_rn(__fmul_rn(dx, dx), __fmul_rn(dy, dy)),
                                __fmul_rn(dz, dz));
            float dd = fminf(dloc[w], d);
            dloc[w] = dd;
            if (dd > bestV) { bestV = dd; bestW = w; }  // strict > : lowest w kept
        }
        int bestN = tid + bestW * NT;   // n grows with w -> min n on tie
        unsigned vmax, iInv;
        wave_argmax(__float_as_uint(bestV), 0xFFFFFFFFu ^ (unsigned)bestN,
                    vmax, iInv);
        const int par = i & 1;
        if (lane == 0)
            wkey[par][wid] = ((unsigned long long)vmax << 32) | iInv;
        __syncthreads();   // single barrier per iteration (parity dbuf)
        unsigned long long kb = wkey[par][0];
#pragma unroll
        for (int w2 = 1; w2 < NW; ++w2) kb = umax64(kb, wkey[par][w2]);
        far = (int)(0xFFFFFFFFu ^ (unsigned)kb);
        float4 cc = scoord[far];   // broadcast, conflict-free
        cx = cc.x; cy = cc.y; cz = cc.z;
    }
}

// ---------------- FPS (single wave, device body, no barriers) ---------------
__device__ void fps_wave_dev(const float* __restrict__ pts, int npoint,
                             int* __restrict__ outIdx, float* __restrict__ outXyz,
                             int b, float4* scoord)
{
    constexpr int ITEMS = 8;
    constexpr int STRIDE = 3;
    constexpr int N = 64 * ITEMS;
    const int tid = threadIdx.x;   // 0..63
    const float* P = pts + (size_t)b * N * STRIDE;

    float px[ITEMS], py[ITEMS], pz[ITEMS], dloc[ITEMS];
#pragma unroll
    for (int w = 0; w < ITEMS; ++w) {
        int n = tid + w * 64;
        float x = P[(size_t)n * STRIDE + 0];
        float y = P[(size_t)n * STRIDE + 1];
        float z = P[(size_t)n * STRIDE + 2];
        px[w] = x; py[w] = y; pz[w] = z;
        scoord[n] = make_float4(x, y, z, 0.f);
        dloc[w] = 1e10f;
    }
    __threadfence_block();
    float4 c0 = scoord[0];
    float cx = c0.x, cy = c0.y, cz = c0.z;
    int far = 0;

    for (int i = 0; i < npoint; ++i) {
        if (tid == 0) {
            outIdx[(size_t)b * npoint + i] = far;
            outXyz[((size_t)b * npoint + i) * 3 + 0] = cx;
            outXyz[((size_t)b * npoint + i) * 3 + 1] = cy;
            outXyz[((size_t)b * npoint + i) * 3 + 2] = cz;
        }
        float bestV = -1.0f;
        int bestW = 0;
#pragma unroll
        for (int w = 0; w < ITEMS; ++w) {
            float dx = __fsub_rn(px[w], cx);
            float dy = __fsub_rn(py[w], cy);
            float dz = __fsub_rn(pz[w], cz);
            float d = __fadd_rn(__fadd_rn(__fmul_rn(dx, dx), __fmul_rn(dy, dy)),
                                __fmul_rn(dz, dz));
            float dd = fminf(dloc[w], d);
            dloc[w] = dd;
            if (dd > bestV) { bestV = dd; bestW = w; }
        }
        int bestN = tid + bestW * 64;
        unsigned vmax, iInv;
        wave_argmax(__float_as_uint(bestV), 0xFFFFFFFFu ^ (unsigned)bestN,
                    vmax, iInv);
        far = (int)(0xFFFFFFFFu ^ iInv);
        float4 cc = scoord[far];
        cx = cc.x; cy = cc.y; cz = cc.z;
    }
}

// ---------------- fused query_ball + group for SA1 (+fps_wave piggyback) ----
__global__ __launch_bounds__(256) void qb_group1(
    const float* __restrict__ xyz /*(8,4096,4)*/,
    const float* __restrict__ ctr /*(8*512,3)*/,
    float* __restrict__ out /*(8*512*32, 8)*/,
    int nQb, const float* __restrict__ fpsPts,
    int* __restrict__ fpsIdx, float* __restrict__ fpsXyz)
{
    __shared__ float4 scoord[512];
    if ((int)blockIdx.x >= nQb) {   // piggyback: single-wave FPS (SA2)
        if (threadIdx.x < 64)
            fps_wave_dev(fpsPts, 128, fpsIdx, fpsXyz,
                         (int)blockIdx.x - nQb, scoord);
        return;
    }
    int gw = (blockIdx.x * 256 + threadIdx.x) >> 6;
    int lane = threadIdx.x & 63;
    if (gw >= 4096) return;
    int b = gw >> 9;
    const float* P = xyz + (size_t)b * 4096 * 4;
    float cx = ctr[(size_t)gw * 3 + 0];
    float cy = ctr[(size_t)gw * 3 + 1];
    float cz = ctr[(size_t)gw * 3 + 2];
    float* out0 = out + (size_t)gw * 32 * 8;
    int cnt = 0;
    float f0x = 0.f, f0y = 0.f, f0z = 0.f, f0t = 0.f;
    bool haveFirst = false;
    for (int base = 0; base < 4096 && cnt < 32; base += 64) {
        int n = base + lane;
        float4 p = *(const float4*)(P + (size_t)n * 4);
        float ex = __fsub_rn(p.x, cx);
        float ey = __fsub_rn(p.y, cy);
        float ez = __fsub_rn(p.z, cz);
        float d = __fadd_rn(__fadd_rn(__fmul_rn(ex, ex), __fmul_rn(ey, ey)),
                            __fmul_rn(ez, ez));
        bool inb = !(d > 0.04f);
        unsigned long long mask = __ballot(inb);
        if (mask) {
            if (!haveFirst) {
                int fl = (int)__builtin_ctzll(mask);   // wave-uniform
                f0x = __shfl(ex, fl); f0y = __shfl(ey, fl);
                f0z = __shfl(ez, fl); f0t = __shfl(p.w, fl);
                haveFirst = true;
            }
            if (inb) {
                int pos = cnt + __builtin_popcountll(mask & ((1ull << lane) - 1ull));
                if (pos < 32) {
                    float* o = out0 + (size_t)pos * 8;
                    *(float4*)o = make_float4(ex, ey, ez, p.w);
                    *(float4*)(o + 4) = make_float4(0.f, 0.f, 0.f, 0.f);
                }
            }
            cnt += (int)__builtin_popcountll(mask);
        }
    }
    if (cnt > 32) cnt = 32;
    for (int p2 = cnt + lane; p2 < 32; p2 += 64) {
        float* o = out0 + (size_t)p2 * 8;
        *(float4*)o = make_float4(f0x, f0y, f0z, f0t);
        *(float4*)(o + 4) = make_float4(0.f, 0.f, 0.f, 0.f);
    }
}

// ---------------- query_ball body (SA2 geometry, device) ----------------
__device__ __forceinline__ void qb2_dev(
    const float* __restrict__ xyz, const float* __restrict__ centers,
    int* __restrict__ outIdx, int gw, int lane)
{
    const int N = 512, stride = 3, S = 128, nsample = 64;
    const float r2 = 0.16f;
    int b = gw / S;
    const float* P = xyz + (size_t)b * N * stride;
    float cx = centers[(size_t)gw * 3 + 0];
    float cy = centers[(size_t)gw * 3 + 1];
    float cz = centers[(size_t)gw * 3 + 2];
    int* out = outIdx + (size_t)gw * nsample;
    int cnt = 0;
    int firstIdx = 0;
    bool haveFirst = false;
    for (int base = 0; base < N && cnt < nsample; base += 64) {
        int n = base + lane;
        bool inb = false;
        if (n < N) {
            float dx = __fsub_rn(cx, P[(size_t)n * stride + 0]);
            float dy = __fsub_rn(cy, P[(size_t)n * stride + 1]);
            float dz = __fsub_rn(cz, P[(size_t)n * stride + 2]);
            float d = __fadd_rn(__fadd_rn(__fmul_rn(dx, dx), __fmul_rn(dy, dy)),
                                __fmul_rn(dz, dz));
            inb = !(d > r2);
        }
        unsigned long long mask = __ballot(inb);
        if (mask) {
            if (!haveFirst) { firstIdx = base + __builtin_ctzll(mask); haveFirst = true; }
            if (inb) {
                int pos = cnt + __builtin_popcountll(mask & ((1ull << lane) - 1ull));
                if (pos < nsample) out[pos] = n;
            }
            cnt += (int)__builtin_popcountll(mask);
        }
    }
    if (cnt > nsample) cnt = nsample;
    for (int p = cnt + lane; p < nsample; p += 64) out[p] = firstIdx;
}

// ---------------- query_ball (standalone, fallback) ----------------
__global__ __launch_bounds__(256) void query_ball_kernel(
    const float* __restrict__ xyz, const float* __restrict__ centers,
    int nCenters, int* __restrict__ outIdx)
{
    int gw = (blockIdx.x * 256 + threadIdx.x) >> 6;
    int lane = threadIdx.x & 63;
    if (gw >= nCenters) return;
    qb2_dev(xyz, centers, outIdx, gw, lane);
}

// ---------------- grouping bodies (device) + standalone fallbacks ----------
__device__ __forceinline__ void group2_body(
    const float* __restrict__ xyz, const float* __restrict__ feat,
    const int* __restrict__ qb, const float* __restrict__ ctr,
    float* __restrict__ out, int i)
{
    int sk = i / 136;
    int c = i - sk * 136;
    int b = sk / (128 * 64);
    int bs = sk / 64;
    int idx = qb[sk];
    idx = (idx < 0) ? 0 : (idx > 511 ? 511 : idx);
    float v = 0.f;
    if (c < 3)        v = __fsub_rn(xyz[((size_t)b * 512 + idx) * 3 + c], ctr[(size_t)bs * 3 + c]);
    else if (c < 131) v = feat[((size_t)b * 512 + idx) * 128 + (c - 3)];
    out[i] = v;
}

__device__ __forceinline__ void group3_body(
    const float* __restrict__ ctr2, const float* __restrict__ feat2,
    float* __restrict__ out, int i)
{
    int sk = i / 264;
    int c = i - sk * 264;
    float v = 0.f;
    if (c < 3)        v = ctr2[(size_t)sk * 3 + c];
    else if (c < 259) v = feat2[(size_t)sk * 256 + (c - 3)];
    out[i] = v;
}

__global__ __launch_bounds__(256) void group2_kernel(
    const float* __restrict__ xyz, const float* __restrict__ feat,
    const int* __restrict__ qb, const float* __restrict__ ctr,
    float* __restrict__ out)
{
    int i = blockIdx.x * 256 + threadIdx.x;
    if (i >= 65536 * 136) return;
    group2_body(xyz, feat, qb, ctr, out, i);
}

__global__ __launch_bounds__(256) void group3_kernel(
    const float* __restrict__ ctr2, const float* __restrict__ feat2,
    float* __restrict__ out)
{
    int i = blockIdx.x * 256 + threadIdx.x;
    if (i >= 1024 * 264) return;
    group3_body(ctr2, feat2, out, i);
}

// ============================================================================
// GEMM tile body (R13 gemm_fused inner, as device fn). One acc set, Y to
// global, stats to part[o*YB + bx]. Bit-identical math/order to R13.
// tstart: first tile id of this block (coop: blockIdx.x; fallback:
// blockIdx.x + blockIdx.y*gridDim.x). Stride G covers ntile.
// ============================================================================
#define GPITCH 40

__device__ void mlp_layer(
    const float* __restrict__ X, const float* __restrict__ scale,
    const float* __restrict__ shift, int applyAct,
    const unsigned short* __restrict__ Bh, const unsigned short* __restrict__ Bl,
    float* __restrict__ Y, double* __restrict__ part,
    int AC, int CPW, int O, int YB, int tstart, int G,
    unsigned short* sAh, unsigned short* sAl,
    unsigned short* sBh, unsigned short* sBl, float* sred)
{
    const int tid = threadIdx.x;
    const int lane = tid & 63;
    const int wid = tid >> 6;
    const int col15 = lane & 15;
    const int quad = lane >> 4;
    const int wm = (wid >> 1) * 64;
    const int wo = (wid & 1) * 64;
    const int lr = tid >> 2;
    const int lc = (tid & 3) * 8;
    const int ntile = YB * ((O + 127) >> 7);

    for (int t = tstart; t < ntile; t += G) {
        const int bx = t % YB;
        const int oy = t / YB;
        const int m0 = bx * 128;
        const int o0 = oy * 128;

        f32x4 acc[4][4];
#pragma unroll
        for (int mt = 0; mt < 4; ++mt)
#pragma unroll
            for (int ot = 0; ot < 4; ++ot)
                acc[mt][ot] = {0.f, 0.f, 0.f, 0.f};

        for (int k0 = 0; k0 < CPW; k0 += 32) {
#pragma unroll
            for (int it = 0; it < 2; ++it) {
                int r = lr + it * 64;
                int c = k0 + lc;
                unsigned short h[8], l[8];
                if (c + 8 <= AC) {
                    const float* xr = X + (size_t)(m0 + r) * AC + c;
                    float4 v0 = *(const float4*)xr;
                    float4 v1 = *(const float4*)(xr + 4);
                    float vv[8] = {v0.x, v0.y, v0.z, v0.w, v1.x, v1.y, v1.z, v1.w};
#pragma unroll
                    for (int j = 0; j < 8; ++j) {
                        float v = vv[j];
                        if (applyAct) v = fmaxf(v * scale[c + j] + shift[c + j], 0.f);
                        f2bf_split(v, h[j], l[j]);
                    }
                } else {
#pragma unroll
                    for (int j = 0; j < 8; ++j) { h[j] = 0; l[j] = 0; }
                }
                *(ushort4*)&sAh[r * GPITCH + lc] = make_ushort4(h[0], h[1], h[2], h[3]);
                *(ushort4*)&sAh[r * GPITCH + lc + 4] = make_ushort4(h[4], h[5], h[6], h[7]);
                *(ushort4*)&sAl[r * GPITCH + lc] = make_ushort4(l[0], l[1], l[2], l[3]);
                *(ushort4*)&sAl[r * GPITCH + lc + 4] = make_ushort4(l[4], l[5], l[6], l[7]);
            }
#pragma unroll
            for (int it = 0; it < 2; ++it) {
                int r = lr + it * 64;
                int c = k0 + lc;
                int o = o0 + r;
                uint4 vh = {0, 0, 0, 0}, vl = {0, 0, 0, 0};
                if (o < O && c < CPW) {
                    size_t goff = (size_t)o * CPW + c;
                    vh = *(const uint4*)(Bh + goff);
                    vl = *(const uint4*)(Bl + goff);
                }
                *(uint4*)&sBh[r * GPITCH + lc] = vh;
                *(uint4*)&sBl[r * GPITCH + lc] = vl;
            }
            __syncthreads();
            s16x8 ah[4], al[4], bh[4], bl[4];
#pragma unroll
            for (int mt = 0; mt < 4; ++mt) {
                int rowoff = (wm + mt * 16 + col15) * GPITCH + quad * 8;
                ah[mt] = *(const s16x8*)&sAh[rowoff];
                al[mt] = *(const s16x8*)&sAl[rowoff];
            }
#pragma unroll
            for (int ot = 0; ot < 4; ++ot) {
                int rowoff = (wo + ot * 16 + col15) * GPITCH + quad * 8;
                bh[ot] = *(const s16x8*)&sBh[rowoff];
                bl[ot] = *(const s16x8*)&sBl[rowoff];
            }
#pragma unroll
            for (int mt = 0; mt < 4; ++mt)
#pragma unroll
                for (int ot = 0; ot < 4; ++ot) {
                    acc[mt][ot] = __builtin_amdgcn_mfma_f32_16x16x32_bf16(
                        ah[mt], bl[ot], acc[mt][ot], 0, 0, 0);
                    acc[mt][ot] = __builtin_amdgcn_mfma_f32_16x16x32_bf16(
                        al[mt], bh[ot], acc[mt][ot], 0, 0, 0);
                    acc[mt][ot] = __builtin_amdgcn_mfma_f32_16x16x32_bf16(
                        ah[mt], bh[ot], acc[mt][ot], 0, 0, 0);
                }
            __syncthreads();
        }
#pragma unroll
        for (int mt = 0; mt < 4; ++mt)
#pragma unroll
            for (int ot = 0; ot < 4; ++ot) {
                int og = o0 + wo + ot * 16 + col15;
                if (og < O) {
#pragma unroll
                    for (int r = 0; r < 4; ++r) {
                        int mg = m0 + wm + mt * 16 + quad * 4 + r;
                        Y[(size_t)mg * O + og] = acc[mt][ot][r];
                    }
                }
            }
        // BN stats epilogue (deterministic fixed-order combine).
#pragma unroll
        for (int ot = 0; ot < 4; ++ot) {
            float s = 0.f, s2 = 0.f;
#pragma unroll
            for (int mt = 0; mt < 4; ++mt)
#pragma unroll
                for (int r = 0; r < 4; ++r) {
                    float v = acc[mt][ot][r];
                    s += v;
                    s2 += v * v;
                }
            int slot = ((wid * 4 + quad) * 16 + col15) * 4 + ot;
            sred[slot * 2] = s;
            sred[slot * 2 + 1] = s2;
        }
        __syncthreads();
        if (tid < 128) {
            int col = tid;
            int o = o0 + col;
            if (o < O) {
                int cb = col >> 6;
                int ot = (col & 63) >> 4;
                int c15 = col & 15;
                double S = 0.0, S2 = 0.0;
#pragma unroll
                for (int wp = 0; wp < 2; ++wp) {
                    int wd = cb + wp * 2;
#pragma unroll
                    for (int q = 0; q < 4; ++q) {
                        int slot = ((wd * 4 + q) * 16 + c15) * 4 + ot;
                        S += (double)sred[slot * 2];
                        S2 += (double)sred[slot * 2 + 1];
                    }
                }
                part[(size_t)o * YB + bx] = S;
                part[(size_t)O * YB + (size_t)o * YB + bx] = S2;
            }
        }
        __syncthreads();   // protect sred before next tile's stats write
    }
}

// finalize (mirrors finalize_bn exactly; stride over channels from ostart)
__device__ void mlp_fin(
    const double* __restrict__ part, int O, int YB,
    const float* __restrict__ g, const float* __restrict__ bb,
    float* __restrict__ scale, float* __restrict__ shift,
    double invM, int ostart, int G, double* sd)
{
    const int tid = threadIdx.x;
    for (int o = ostart; o < O; o += G) {
        double s = 0.0, s2 = 0.0;
        for (int yb = tid; yb < YB; yb += 256) {
            s  += part[(size_t)o * YB + yb];
            s2 += part[(size_t)O * YB + (size_t)o * YB + yb];
        }
        sd[tid] = s;
        sd[256 + tid] = s2;
        __syncthreads();
#pragma unroll
        for (int st = 128; st > 0; st >>= 1) {
            if (tid < st) {
                sd[tid] += sd[tid + st];
                sd[256 + tid] += sd[256 + tid + st];
            }
            __syncthreads();
        }
        if (tid == 0) {
            double mean = sd[0] * invM;
            double var = sd[256] * invM - mean * mean;
            float varf = (float)var;
            if (varf < 0.f) varf = 0.f;
            float sc = g[o] * rsqrtf(varf + 1e-5f);
            scale[o] = sc;
            shift[o] = bb[o] - (float)mean * sc;
        }
        __syncthreads();   // sd reuse across o-iterations
    }
}

// ---------------- cooperative 3-layer MLP (one per SA stage) ----------------
struct MlpArgs {
    // pre-phase: 0 none, 2 group2, 3 group3
    int preMode;
    const float* preXyz; const float* preFeat; const int* preQb;
    const float* preCtr; float* preOut;
    // layers
    const float* X0; float* Y0; float* Y1; float* Y2;
    const unsigned short *Bh0, *Bl0, *Bh1, *Bl1, *Bh2, *Bl2;
    const float *g0, *bb0, *g1, *bb1, *g2, *bb2;
    float *sc0, *sh0, *sc1, *sh1, *sc2, *sh2;
    double* part; double invM;
    int YB;
    int AC0, CPW0, O0, AC1, CPW1, O1, AC2, CPW2, O2;
    // epilogue (bn_relu_max)
    int K, Stot; float* feat;
    // sync-free tail: SA2 query_ball
    int doQB;
    const float* qbXyz; const float* qbCtr; int* qbOut;
};

__global__ __launch_bounds__(256, 2) void mlp_coop(MlpArgs a)
{
    __shared__ __align__(16) unsigned short sAh[128 * GPITCH];
    __shared__ __align__(16) unsigned short sAl[128 * GPITCH];
    __shared__ __align__(16) unsigned short sBh[128 * GPITCH];
    __shared__ __align__(16) unsigned short sBl[128 * GPITCH];
    __shared__ __align__(16) float sred[2048];
    cg::grid_group grid = cg::this_grid();
    const int G = gridDim.x;
    const int bid = blockIdx.x;
    const int tid = threadIdx.x;

    if (a.preMode == 2) {
        for (int i = bid * 256 + tid; i < 65536 * 136; i += G * 256)
            group2_body(a.preXyz, a.preFeat, a.preQb, a.preCtr, a.preOut, i);
        __threadfence(); grid.sync();
    } else if (a.preMode == 3) {
        for (int i = bid * 256 + tid; i < 1024 * 264; i += G * 256)
            group3_body(a.preCtr, a.preFeat, a.preOut, i);
        __threadfence(); grid.sync();
    }

    mlp_layer(a.X0, nullptr, nullptr, 0, a.Bh0, a.Bl0, a.Y0, a.part,
              a.AC0, a.CPW0, a.O0, a.YB, bid, G, sAh, sAl, sBh, sBl, sred);
    __threadfence(); grid.sync();
    mlp_fin(a.part, a.O0, a.YB, a.g0, a.bb0, a.sc0, a.sh0, a.invM, bid, G,
            (double*)sred);
    __threadfence(); grid.sync();

    mlp_layer(a.Y0, a.sc0, a.sh0, 1, a.Bh1, a.Bl1, a.Y1, a.part,
              a.AC1, a.CPW1, a.O1, a.YB, bid, G, sAh, sAl, sBh, sBl, sred);
    __threadfence(); grid.sync();
    mlp_fin(a.part, a.O1, a.YB, a.g1, a.bb1, a.sc1, a.sh1, a.invM, bid, G,
            (double*)sred);
    __threadfence(); grid.sync();

    mlp_layer(a.Y1, a.sc1, a.sh1, 1, a.Bh2, a.Bl2, a.Y2, a.part,
              a.AC2, a.CPW2, a.O2, a.YB, bid, G, sAh, sAl, sBh, sBl, sred);
    __threadfence(); grid.sync();
    mlp_fin(a.part, a.O2, a.YB, a.g2, a.bb2, a.sc2, a.sh2, a.invM, bid, G,
            (double*)sred);
    __threadfence(); grid.sync();

    // epilogue: BN + ReLU + max over K (identical math to bn_relu_max)
    {
        const int total = a.Stot * a.O2;
        for (int idx = bid * 256 + tid; idx < total; idx += G * 256) {
            int s = idx / a.O2;
            int o = idx - s * a.O2;
            const float* basep = a.Y2 + (size_t)s * a.K * a.O2 + o;
            float sc = a.sc2[o], sh = a.sh2[o];
            float mx = 0.f;
            for (int k = 0; k < a.K; ++k) {
                float v = basep[(size_t)k * a.O2] * sc + sh;
                v = fmaxf(v, 0.f);
                mx = fmaxf(mx, v);
            }
            a.feat[idx] = mx;
        }
    }

    // sync-free tail: SA2 query_ball (inputs from prior dispatches; output
    // consumed by the next dispatch — no in-kernel ordering needed).
    if (a.doQB) {
        const int wv = tid >> 6, lane = tid & 63;
        for (int gw = bid * 4 + wv; gw < 1024; gw += G * 4)
            qb2_dev(a.qbXyz, a.qbCtr, a.qbOut, gw, lane);
    }
}

// ---------------- fallback kernels (R13 chain, FIXED tile mapping) ----------
__global__ __launch_bounds__(256) void gemm_fused(
    const float* __restrict__ X,
    const float* __restrict__ scale, const float* __restrict__ shift,
    int applyAct,
    const unsigned short* __restrict__ Bh, const unsigned short* __restrict__ Bl,
    float* __restrict__ Y, double* __restrict__ part,
    int M, int AC, int CPW, int O, int YBmain)
{
    __shared__ __align__(16) unsigned short sAh[128 * GPITCH];
    __shared__ __align__(16) unsigned short sAl[128 * GPITCH];
    __shared__ __align__(16) unsigned short sBh[128 * GPITCH];
    __shared__ __align__(16) unsigned short sBl[128 * GPITCH];
    __shared__ __align__(16) float sred[2048];
    // R16 FIX: tstart encodes BOTH grid dims; grid == ntile -> exactly one
    // tile per block (R13-exact). R15 ignored blockIdx.y here -> half the
    // tiles never computed on OB>1 launches.
    const int tstart = blockIdx.x + blockIdx.y * gridDim.x;
    const int G = gridDim.x * gridDim.y;
    mlp_layer(X, scale, shift, applyAct, Bh, Bl, Y, part, AC, CPW, O, YBmain,
              tstart, G, sAh, sAl, sBh, sBl, sred);
}

__global__ __launch_bounds__(256) void finalize_bn(
    const double* __restrict__ part, const float* __restrict__ g,
    const float* __restrict__ bb, float* __restrict__ scale,
    float* __restrict__ shift, int O, int YB, double invM)
{
    __shared__ double sd[512];
    mlp_fin(part, O, YB, g, bb, scale, shift, invM, blockIdx.x, gridDim.x, sd);
}

__global__ __launch_bounds__(256) void bn_relu_max(
    const float* __restrict__ Y, const float* __restrict__ scale,
    const float* __restrict__ shift, float* __restrict__ out,
    int Stot, int K, int O)
{
    int idx = blockIdx.x * 256 + threadIdx.x;
    if (idx >= Stot * O) return;
    int s = idx / O;
    int o = idx - s * O;
    const float* basep = Y + (size_t)s * K * O + o;
    float sc = scale[o], sh = shift[o];
    float mx = 0.f;
    for (int k = 0; k < K; ++k) {
        float v = basep[(size_t)k * O] * sc + sh;
        v = fmaxf(v, 0.f);
        mx = fmaxf(mx, v);
    }
    out[idx] = mx;
}

// ============================================================================
extern "C" void kernel_launch(void* const* d_in, const int* in_sizes, int n_in,
                              void* d_out, int out_size, void* d_ws, size_t ws_size,
                              hipStream_t stream)
{
    const float* xin = (const float*)d_in[0];
    const float* w[9]; const float* g[9]; const float* bb[9];
    for (int i = 0; i < 9; ++i) {
        w[i]  = (const float*)d_in[1 + 3 * i];
        g[i]  = (const float*)d_in[2 + 3 * i];
        bb[i] = (const float*)d_in[3 + 3 * i];
    }

    char* base = (char*)d_ws;
    size_t off = 0;
    auto alloc = [&](size_t bytes) -> void* {
        void* p = base + off;
        off = (off + bytes + 255) & ~(size_t)255;
        return p;
    };
    const int OC[9][3] = {{64,4,8},{64,64,64},{128,64,64},
                          {128,131,136},{128,128,128},{256,128,128},
                          {256,259,264},{512,256,256},{1024,512,512}};
    size_t woff[10]; woff[0] = 0;
    for (int i = 0; i < 9; ++i) woff[i + 1] = woff[i] + (size_t)OC[i][0] * OC[i][2];

    // --- small / metadata region (memset-protected) ---
    int*    fps1   = (int*)alloc((size_t)4096 * 4);
    int*    fps2   = (int*)alloc((size_t)1024 * 4);
    int*    qb2    = (int*)alloc((size_t)65536 * 4);
    float*  nx1    = (float*)alloc((size_t)12288 * 4);
    float*  nx2    = (float*)alloc((size_t)3072 * 4);
    float*  feat1  = (float*)alloc((size_t)524288 * 4);
    float*  feat2  = (float*)alloc((size_t)262144 * 4);
    double* part   = (double*)alloc((size_t)262144 * 8);
    float*  scales = (float*)alloc((size_t)9 * 1024 * 4);
    float*  shifts = (float*)alloc((size_t)9 * 1024 * 4);
    unsigned short* WH = (unsigned short*)alloc(woff[9] * 2);
    unsigned short* WL = (unsigned short*)alloc(woff[9] * 2);
    const size_t zeroBytes = off;
    // --- big ping/pong buffers ---
    float*  XG = (float*)alloc((size_t)65536 * 136 * 4);
    float*  A  = (float*)alloc((size_t)16777216 * 4);
    if (off > ws_size) return;

    hipMemsetAsync(d_ws, 0, zeroBytes, stream);

    PWArgs pwa;
    for (int i = 0; i < 9; ++i) {
        pwa.w[i] = w[i]; pwa.off[i] = (unsigned)woff[i];
        pwa.O[i] = OC[i][0]; pwa.C[i] = OC[i][1]; pwa.CP[i] = OC[i][2];
    }
    const int nPrep = (int)((woff[9] + 255) / 256);

    // ---------------- SA1 front ----------------
    fps_block<256, 16, 4><<<8 + nPrep, 256, 0, stream>>>(
        xin, 512, fps1, nx1, 8, pwa, WH, WL, (int)woff[9]);
    qb_group1<<<1024 + 8, 256, 0, stream>>>(xin, nx1, XG, 1024, nx1, fps2, nx2);

    // ---------------- coop grid sizing (occupancy-based, capture-safe) -----
    int coopGrid = 0;
    {
        int nb = 0;
        if (hipOccupancyMaxActiveBlocksPerMultiprocessor(
                &nb, (const void*)mlp_coop, 256, 0) == hipSuccess && nb >= 1) {
            long long total = (long long)nb * 256;   // 256 CUs on MI355X
            coopGrid = (int)(total < 512 ? total : 512);
        }
    }
    auto launch_coop = [&](MlpArgs& m) -> bool {
        if (coopGrid < 1) return false;
        void* ka[] = {(void*)&m};
        hipError_t e = hipLaunchCooperativeKernel(
            (const void*)mlp_coop, dim3(coopGrid), dim3(256), ka, 0, stream);
        return e == hipSuccess;
    };
    auto fb_layer = [&](const float* X, const float* sc, const float* sh,
                        int act, int wi, float* Y, int M, int AC, int CPW,
                        int O, int YB, int li, double invM) {
        gemm_fused<<<dim3(YB, (O + 127) / 128), 256, 0, stream>>>(
            X, sc, sh, act, WH + woff[wi], WL + woff[wi], Y, part,
            M, AC, CPW, O, YB);
        finalize_bn<<<O, 256, 0, stream>>>(part, g[wi], bb[wi],
            scales + li * 1024, shifts + li * 1024, O, YB, invM);
    };

    // ---- SA1 MLP (+ query_ball tail) ----
    {
        MlpArgs m = {};
        m.preMode = 0;
        m.X0 = XG; m.Y0 = A; m.Y1 = XG; m.Y2 = A;
        m.Bh0 = WH + woff[0]; m.Bl0 = WL + woff[0];
        m.Bh1 = WH + woff[1]; m.Bl1 = WL + woff[1];
        m.Bh2 = WH + woff[2]; m.Bl2 = WL + woff[2];
        m.g0 = g[0]; m.bb0 = bb[0]; m.g1 = g[1]; m.bb1 = bb[1];
        m.g2 = g[2]; m.bb2 = bb[2];
        m.sc0 = scales + 0;    m.sh0 = shifts + 0;
        m.sc1 = scales + 1024; m.sh1 = shifts + 1024;
        m.sc2 = scales + 2048; m.sh2 = shifts + 2048;
        m.part = part; m.invM = 1.0 / 131072.0; m.YB = 1024;
        m.AC0 = 8;  m.CPW0 = 8;  m.O0 = 64;
        m.AC1 = 64; m.CPW1 = 64; m.O1 = 64;
        m.AC2 = 64; m.CPW2 = 64; m.O2 = 128;
        m.K = 32; m.Stot = 4096; m.feat = feat1;
        m.doQB = 1; m.qbXyz = nx1; m.qbCtr = nx2; m.qbOut = qb2;
        if (!launch_coop(m)) {
            fb_layer(XG, nullptr, nullptr, 0, 0, A, 131072, 8, 8, 64, 1024, 0, 1.0 / 131072.0);
            fb_layer(A, scales + 0, shifts + 0, 1, 1, XG, 131072, 64, 64, 64, 1024, 1, 1.0 / 131072.0);
            fb_layer(XG, scales + 1024, shifts + 1024, 1, 2, A, 131072, 64, 64, 128, 1024, 2, 1.0 / 131072.0);
            bn_relu_max<<<(4096 * 128) / 256, 256, 0, stream>>>(A, scales + 2048, shifts + 2048, feat1, 4096, 32, 128);
            query_ball_kernel<<<(8 * 128 * 64) / 256, 256, 0, stream>>>(nx1, nx2, 1024, qb2);
        }
    }

    // ---- SA2 MLP (group2 pre-phase) ----
    {
        MlpArgs m = {};
        m.preMode = 2;
        m.preXyz = nx1; m.preFeat = feat1; m.preQb = qb2; m.preCtr = nx2;
        m.preOut = XG;
        m.X0 = XG; m.Y0 = A; m.Y1 = XG; m.Y2 = A;
        m.Bh0 = WH + woff[3]; m.Bl0 = WL + woff[3];
        m.Bh1 = WH + woff[4]; m.Bl1 = WL + woff[4];
        m.Bh2 = WH + woff[5]; m.Bl2 = WL + woff[5];
        m.g0 = g[3]; m.bb0 = bb[3]; m.g1 = g[4]; m.bb1 = bb[4];
        m.g2 = g[5]; m.bb2 = bb[5];
        m.sc0 = scales + 3072; m.sh0 = shifts + 3072;
        m.sc1 = scales + 4096; m.sh1 = shifts + 4096;
        m.sc2 = scales + 5120; m.sh2 = shifts + 5120;
        m.part = part; m.invM = 1.0 / 65536.0; m.YB = 512;
        m.AC0 = 136; m.CPW0 = 136; m.O0 = 128;
        m.AC1 = 128; m.CPW1 = 128; m.O1 = 128;
        m.AC2 = 128; m.CPW2 = 128; m.O2 = 256;
        m.K = 64; m.Stot = 1024; m.feat = feat2;
        m.doQB = 0;
        if (!launch_coop(m)) {
            group2_kernel<<<(65536 * 136) / 256, 256, 0, stream>>>(nx1, feat1, qb2, nx2, XG);
            fb_layer(XG, nullptr, nullptr, 0, 3, A, 65536, 136, 136, 128, 512, 3, 1.0 / 65536.0);
            fb_layer(A, scales + 3072, shifts + 3072, 1, 4, XG, 65536, 128, 128, 128, 512, 4, 1.0 / 65536.0);
            fb_layer(XG, scales + 4096, shifts + 4096, 1, 5, A, 65536, 128, 128, 256, 512, 5, 1.0 / 65536.0);
            bn_relu_max<<<(1024 * 256) / 256, 256, 0, stream>>>(A, scales + 5120, shifts + 5120, feat2, 1024, 64, 256);
        }
    }

    // ---- SA3 MLP (group3 pre-phase) ----
    {
        MlpArgs m = {};
        m.preMode = 3;
        m.preCtr = nx2; m.preFeat = feat2; m.preOut = XG;
        m.X0 = XG; m.Y0 = A; m.Y1 = XG; m.Y2 = A;
        m.Bh0 = WH + woff[6]; m.Bl0 = WL + woff[6];
        m.Bh1 = WH + woff[7]; m.Bl1 = WL + woff[7];
        m.Bh2 = WH + woff[8]; m.Bl2 = WL + woff[8];
        m.g0 = g[6]; m.bb0 = bb[6]; m.g1 = g[7]; m.bb1 = bb[7];
        m.g2 = g[8]; m.bb2 = bb[8];
        m.sc0 = scales + 6144; m.sh0 = shifts + 6144;
        m.sc1 = scales + 7168; m.sh1 = shifts + 7168;
        m.sc2 = scales + 8192; m.sh2 = shifts + 8192;
        m.part = part; m.invM = 1.0 / 1024.0; m.YB = 8;
        m.AC0 = 264; m.CPW0 = 264; m.O0 = 256;
        m.AC1 = 256; m.CPW1 = 256; m.O1 = 512;
        m.AC2 = 512; m.CPW2 = 512; m.O2 = 1024;
        m.K = 128; m.Stot = 8; m.feat = (float*)d_out;
        m.doQB = 0;
        if (!launch_coop(m)) {
            group3_kernel<<<(1024 * 264) / 256, 256, 0, stream>>>(nx2, feat2, XG);
            fb_layer(XG, nullptr, nullptr, 0, 6, A, 1024, 264, 264, 256, 8, 6, 1.0 / 1024.0);
            fb_layer(A, scales + 6144, shifts + 6144, 1, 7, XG, 1024, 256, 256, 512, 8, 7, 1.0 / 1024.0);
            fb_layer(XG, scales + 7168, shifts + 7168, 1, 8, A, 1024, 512, 512, 1024, 8, 8, 1.0 / 1024.0);
            bn_relu_max<<<(8 * 1024) / 256, 256, 0, stream>>>(A, scales + 8192, shifts + 8192, (float*)d_out, 8, 128, 1024);
        }
    }
}